// Round 3
// baseline (61.637 us; speedup 1.0000x reference)
//
#include <hip/hip_runtime.h>

// SoftClusterGaussianHead — one-pass moment formulation.
// B=8, N=4096, D=512, K=8.
// sigma = S2 + (S0-2)*S1^2 with S0=sum_n p, S1=sum_n p*x, S2=sum_n p*x^2.
// Round 3: fit acc[8][8]v2f + wk fully in arch VGPRs (256-thread blocks,
// launch_bounds(256,1) -> 512-unit budget) to kill accvgpr/scratch shuffles.

typedef float v2f __attribute__((ext_vector_type(2)));

#define B_ 8
#define N_ 4096
#define D_ 512
#define K_ 8
#define EPS_ 1e-6f
#define CHUNKS 64          // blocks per b
#define WAVES 4            // per block
#define ROWS_PER_WAVE 16   // 64 rows/block / 4 waves

// ws layout (floats), cstride = CHUNKS normally, 1 in atomic fallback:
//   partial: [b][chunk][k][d][2]   (S1,S2 interleaved)   B*cstride*K*D*2
//   s0p:     [b][chunk][k]                               B*cstride*K

__global__ __launch_bounds__(256, 1)
void k1_accum(const float* __restrict__ x, const float* __restrict__ W,
              const float* __restrict__ bias, float* __restrict__ ws,
              int cstride, int atomic_mode) {
  const int lane = threadIdx.x & 63;
  const int wave = threadIdx.x >> 6;
  const int b    = blockIdx.x >> 6;
  const int chunk= blockIdx.x & 63;
  const int m    = lane & 7;

  const int d0 = lane * 4;           // owned d: d0..d0+3 and 256+d0..256+d0+3

  // Preload W fragments: wk[dj][kp] = (W[d][2kp], W[d][2kp+1])
  v2f wk[8][4];
#pragma unroll
  for (int c = 0; c < 4; ++c) {
    const float4* wr0 = reinterpret_cast<const float4*>(&W[(d0 + c) * K_]);
    float4 wa = wr0[0], wb = wr0[1];
    wk[c][0] = (v2f){wa.x, wa.y}; wk[c][1] = (v2f){wa.z, wa.w};
    wk[c][2] = (v2f){wb.x, wb.y}; wk[c][3] = (v2f){wb.z, wb.w};
    const float4* wr1 = reinterpret_cast<const float4*>(&W[(256 + d0 + c) * K_]);
    float4 wc = wr1[0], wd = wr1[1];
    wk[4+c][0] = (v2f){wc.x, wc.y}; wk[4+c][1] = (v2f){wc.z, wc.w};
    wk[4+c][2] = (v2f){wd.x, wd.y}; wk[4+c][3] = (v2f){wd.z, wd.w};
  }
  const float biasv = bias[m];

  v2f acc[8][8];
#pragma unroll
  for (int dj = 0; dj < 8; ++dj)
#pragma unroll
    for (int k = 0; k < 8; ++k) acc[dj][k] = (v2f){0.f, 0.f};
  float s0acc = 0.f;

  const bool c0 = (lane & 1) != 0;
  const bool c1 = (lane & 2) != 0;
  const bool c2 = (lane & 4) != 0;

  const int row_base = chunk * (WAVES * ROWS_PER_WAVE) + wave * ROWS_PER_WAVE;
  const float* xb = x + (size_t)b * N_ * D_;

  // software-pipelined row loop
  const float4* xr = reinterpret_cast<const float4*>(&xb[(size_t)row_base * D_]);
  float4 xa = xr[lane];
  float4 xc = xr[64 + lane];

  for (int i = 0; i < ROWS_PER_WAVE; ++i) {
    // prefetch next row (clamped, no OOB)
    const int nrow = row_base + ((i + 1 < ROWS_PER_WAVE) ? i + 1 : i);
    const float4* xrn = reinterpret_cast<const float4*>(&xb[(size_t)nrow * D_]);
    float4 na = xrn[lane];
    float4 nc = xrn[64 + lane];

    float xv[8] = {xa.x, xa.y, xa.z, xa.w, xc.x, xc.y, xc.z, xc.w};

    // partial logits over owned d
    v2f qp[4] = {(v2f){0,0},(v2f){0,0},(v2f){0,0},(v2f){0,0}};
#pragma unroll
    for (int dj = 0; dj < 8; ++dj) {
      v2f xx = (v2f){xv[dj], xv[dj]};
#pragma unroll
      for (int kp = 0; kp < 4; ++kp) qp[kp] += wk[dj][kp] * xx;
    }
    float q0=qp[0].x,q1=qp[0].y,q2=qp[1].x,q3=qp[1].y;
    float q4=qp[2].x,q5=qp[2].y,q6=qp[3].x,q7=qp[3].y;

    // reduce-scatter butterfly: lane ends with full logit for k = lane&7
    float r0 = c0 ? q0 : q1, r1 = c0 ? q2 : q3, r2 = c0 ? q4 : q5, r3 = c0 ? q6 : q7;
    r0 = __shfl_xor(r0, 1, 64); r1 = __shfl_xor(r1, 1, 64);
    r2 = __shfl_xor(r2, 1, 64); r3 = __shfl_xor(r3, 1, 64);
    float a0 = (c0 ? q1 : q0) + r0, a1 = (c0 ? q3 : q2) + r1;
    float a2 = (c0 ? q5 : q4) + r2, a3 = (c0 ? q7 : q6) + r3;
    float s0g = c1 ? a0 : a1, s1g = c1 ? a2 : a3;
    s0g = __shfl_xor(s0g, 2, 64); s1g = __shfl_xor(s1g, 2, 64);
    float b0 = (c1 ? a1 : a0) + s0g, b1 = (c1 ? a3 : a2) + s1g;
    float g0 = c2 ? b0 : b1;
    g0 = __shfl_xor(g0, 4, 64);
    float t = (c2 ? b1 : b0) + g0;
    t += __shfl_xor(t, 8, 64);
    t += __shfl_xor(t, 16, 64);
    t += __shfl_xor(t, 32, 64);
    t += biasv;

    // softmax in transposed (one-k-per-lane) form
    float mx = fmaxf(t, __shfl_xor(t, 1, 64));
    mx = fmaxf(mx, __shfl_xor(mx, 2, 64));
    mx = fmaxf(mx, __shfl_xor(mx, 4, 64));
    float e = __expf(t - mx);
    float se = e + __shfl_xor(e, 1, 64);
    se += __shfl_xor(se, 2, 64);
    se += __shfl_xor(se, 4, 64);
    float pm = e * __builtin_amdgcn_rcpf(se);
    s0acc += pm;

    // gather p[0..7] to every lane: src = (lane & 0x18) | k within 32-half
    float p[8];
#define GATH(KK) p[KK] = __int_as_float(__builtin_amdgcn_ds_swizzle(__float_as_int(pm), ((KK) << 5) | 0x18))
    GATH(0); GATH(1); GATH(2); GATH(3); GATH(4); GATH(5); GATH(6); GATH(7);
#undef GATH

    // accumulate packed (S1,S2)
#pragma unroll
    for (int dj = 0; dj < 8; ++dj) {
      v2f m2 = (v2f){xv[dj], xv[dj] * xv[dj]};
#pragma unroll
      for (int k = 0; k < 8; ++k) {
        v2f pp = (v2f){p[k], p[k]};
        acc[dj][k] += m2 * pp;
      }
    }

    xa = na; xc = nc;
  }

  // ---- block-level reduction & flush (no global atomics in normal mode) ----
  float* partial = ws;
  float* s0p = ws + (size_t)B_ * cstride * K_ * D_ * 2;
  const int cslot = atomic_mode ? 0 : chunk;

  __shared__ float s0sh[WAVES][K_];
  __shared__ v2f sh[WAVES][2][K_][64];   // 32 KB

  if (lane < K_) s0sh[wave][lane] = s0acc;   // s0acc is wave-complete (replicated per k-lane)
  __syncthreads();
  if (threadIdx.x < K_) {
    float s = 0.f;
#pragma unroll
    for (int w = 0; w < WAVES; ++w) s += s0sh[w][threadIdx.x];
    float* dst = s0p + (size_t)(b * cstride + cslot) * K_ + threadIdx.x;
    if (atomic_mode) atomicAdd(dst, s); else *dst = s;
  }

  const int kred = threadIdx.x >> 5;   // 0..7
  const int sub  = threadIdx.x & 31;   // 0..31

#pragma unroll
  for (int r = 0; r < 4; ++r) {
#pragma unroll
    for (int k = 0; k < 8; ++k) {
      sh[wave][0][k][lane] = acc[2*r][k];
      sh[wave][1][k][lane] = acc[2*r + 1][k];
    }
    __syncthreads();
#pragma unroll
    for (int half = 0; half < 2; ++half) {
      const int slot = sub + 32 * half;
      v2f sA = sh[0][0][kred][slot];
      v2f sB = sh[0][1][kred][slot];
#pragma unroll
      for (int w = 1; w < WAVES; ++w) {
        sA += sh[w][0][kred][slot];
        sB += sh[w][1][kred][slot];
      }
      // dj pair (2r,2r+1) of lane-slot `slot` maps to d:
      const int dbase = (r < 2) ? (slot * 4 + 2 * r) : (256 + slot * 4 + 2 * (r - 2));
      float* dst = partial + (((size_t)(b * cstride + cslot) * K_ + kred) * D_ + dbase) * 2;
      if (atomic_mode) {
        atomicAdd(dst + 0, sA.x); atomicAdd(dst + 1, sA.y);
        atomicAdd(dst + 2, sB.x); atomicAdd(dst + 3, sB.y);
      } else {
        float4 v; v.x = sA.x; v.y = sA.y; v.z = sB.x; v.w = sB.y;
        *reinterpret_cast<float4*>(dst) = v;   // dbase even -> 16B aligned
      }
    }
    __syncthreads();
  }
}

// Fused finalizer: grid = B*32 blocks, 128 threads (8 k x 16 d).
__global__ __launch_bounds__(128)
void k2_final(const float* __restrict__ ws, const float* __restrict__ eps,
              float* __restrict__ out, int cstride, int nchunks) {
  const int b = blockIdx.x >> 5;
  const int slice = blockIdx.x & 31;
  const int tid = threadIdx.x;
  const int k = tid >> 4;
  const int dl = tid & 15;
  const int d = slice * 16 + dl;

  const float* partial = ws;
  const float* s0p = ws + (size_t)B_ * cstride * K_ * D_ * 2;

  __shared__ float s0sh[K_];
  __shared__ float zsh[K_][16];
  __shared__ float klsh[2];

  if (tid < K_) {
    float s = 0.f;
    for (int c = 0; c < nchunks; ++c) s += s0p[(size_t)(b * cstride + c) * K_ + tid];
    s0sh[tid] = s;
  }
  __syncthreads();

  float S1 = 0.f, S2 = 0.f;
  for (int c = 0; c < nchunks; ++c) {
    const v2f v = *reinterpret_cast<const v2f*>(
        partial + (((size_t)(b * cstride + c) * K_ + k) * D_ + d) * 2);
    S1 += v.x; S2 += v.y;
  }
  const float S0 = s0sh[k];
  float sigraw = S2 + (S0 - 2.f) * S1 * S1;
  float sig = fmaxf(sigraw, 0.f) + EPS_;
  float z = S1 + eps[((size_t)(b * K_ + k)) * D_ + d] * sqrtf(sig);
  zsh[k][dl] = z;
  float klp = 1.f + logf(sig) - S1 * S1 - sigraw;

  klp += __shfl_xor(klp, 1, 64);
  klp += __shfl_xor(klp, 2, 64);
  klp += __shfl_xor(klp, 4, 64);
  klp += __shfl_xor(klp, 8, 64);
  klp += __shfl_xor(klp, 16, 64);
  klp += __shfl_xor(klp, 32, 64);
  const int lane = tid & 63, wv = tid >> 6;
  if (lane == 0) klsh[wv] = klp;
  __syncthreads();

  if (tid < 16) {
    float pooled = 0.f;
#pragma unroll
    for (int kk = 0; kk < K_; ++kk) pooled += zsh[kk][tid];
    out[b * D_ + slice * 16 + tid] = pooled * 0.125f;
  }
  if (tid == 0) {
    atomicAdd(out + B_ * D_, (klsh[0] + klsh[1]) * (-0.5f / (B_ * K_)));
  }
}

extern "C" void kernel_launch(void* const* d_in, const int* in_sizes, int n_in,
                              void* d_out, int out_size, void* d_ws, size_t ws_size,
                              hipStream_t stream) {
  const float* x    = (const float*)d_in[0];
  const float* W    = (const float*)d_in[1];
  const float* bias = (const float*)d_in[2];
  const float* eps  = (const float*)d_in[3];
  float* out = (float*)d_out;
  float* ws  = (float*)d_ws;

  const size_t full_floats = (size_t)B_ * CHUNKS * K_ * D_ * 2 + (size_t)B_ * CHUNKS * K_;
  const int atomic_mode = (ws_size < full_floats * sizeof(float)) ? 1 : 0;
  const int cstride = atomic_mode ? 1 : CHUNKS;
  const int nchunks = atomic_mode ? 1 : CHUNKS;

  if (atomic_mode) {
    const size_t zbytes = ((size_t)B_ * 1 * K_ * D_ * 2 + (size_t)B_ * 1 * K_) * sizeof(float);
    hipMemsetAsync(ws, 0, zbytes, stream);
  }
  hipMemsetAsync(out + B_ * D_, 0, sizeof(float), stream);

  k1_accum<<<B_ * CHUNKS, 64 * WAVES, 0, stream>>>(x, W, bias, ws, cstride, atomic_mode);
  k2_final<<<B_ * 32, 128, 0, stream>>>(ws, eps, out, cstride, nchunks);
}

// Round 4
// 61.252 us; speedup vs baseline: 1.0063x; 1.0063x over previous
//
#include <hip/hip_runtime.h>

// SoftClusterGaussianHead — one-pass moment formulation, split into two
// register-lean passes to avoid AGPR/scratch splitting of the accumulator.
// B=8, N=4096, D=512, K=8.
// sigma = S2 + (S0-2)*S1^2 with S0=sum_n p, S1=sum_n p*x, S2=sum_n p*x^2.
// ws: P[B][N][K] | partial[b][chunk][k][d][2] | s0p[b][chunk][k]

typedef float v2f __attribute__((ext_vector_type(2)));

#define B_ 8
#define N_ 4096
#define D_ 512
#define K_ 8
#define EPS_ 1e-6f
#define CHUNKS 32
#define WAVES 8
#define ROWS_PER_WAVE 16   // 128 rows/block / 8 waves

#define P_FLOATS ((size_t)B_ * N_ * K_)

__global__ __launch_bounds__(512, 2)
void kA_probs(const float* __restrict__ x, const float* __restrict__ W,
              const float* __restrict__ bias, float* __restrict__ P,
              float* __restrict__ s0p, int cstride, int atomic_mode) {
#pragma clang fp contract(fast)
  const int lane = threadIdx.x & 63;
  const int wave = threadIdx.x >> 6;
  const int b    = blockIdx.x >> 5;
  const int chunk= blockIdx.x & 31;
  const int m    = lane & 7;
  const int grp  = lane >> 3;
  const int d0   = lane * 4;

  // Preload W fragments: wk[dj][kp] = (W[d][2kp], W[d][2kp+1])
  v2f wk[8][4];
#pragma unroll
  for (int c = 0; c < 4; ++c) {
    const float4* wr0 = reinterpret_cast<const float4*>(&W[(d0 + c) * K_]);
    float4 wa = wr0[0], wb = wr0[1];
    wk[c][0] = (v2f){wa.x, wa.y}; wk[c][1] = (v2f){wa.z, wa.w};
    wk[c][2] = (v2f){wb.x, wb.y}; wk[c][3] = (v2f){wb.z, wb.w};
    const float4* wr1 = reinterpret_cast<const float4*>(&W[(256 + d0 + c) * K_]);
    float4 wc = wr1[0], wd = wr1[1];
    wk[4+c][0] = (v2f){wc.x, wc.y}; wk[4+c][1] = (v2f){wc.z, wc.w};
    wk[4+c][2] = (v2f){wd.x, wd.y}; wk[4+c][3] = (v2f){wd.z, wd.w};
  }
  const float biasv = bias[m];

  const bool c0 = (lane & 1) != 0;
  const bool c1 = (lane & 2) != 0;
  const bool c2 = (lane & 4) != 0;

  const int row_base = chunk * (WAVES * ROWS_PER_WAVE) + wave * ROWS_PER_WAVE;
  const float* xb = x + (size_t)b * N_ * D_;
  float* Pb = P + ((size_t)b * N_ + row_base) * K_;

  float s0acc = 0.f;

  for (int batch = 0; batch < 2; ++batch) {
    float psel = 0.f;
#pragma unroll
    for (int j = 0; j < 8; ++j) {
      const int row = row_base + batch * 8 + j;
      const float4* xr = reinterpret_cast<const float4*>(&xb[(size_t)row * D_]);
      float4 xa = xr[lane];
      float4 xc = xr[64 + lane];
      float xv[8] = {xa.x, xa.y, xa.z, xa.w, xc.x, xc.y, xc.z, xc.w};

      v2f qp[4] = {(v2f){0,0},(v2f){0,0},(v2f){0,0},(v2f){0,0}};
#pragma unroll
      for (int dj = 0; dj < 8; ++dj) {
        v2f xx = (v2f){xv[dj], xv[dj]};
#pragma unroll
        for (int kp = 0; kp < 4; ++kp) qp[kp] += wk[dj][kp] * xx;
      }
      float q0=qp[0].x,q1=qp[0].y,q2=qp[1].x,q3=qp[1].y;
      float q4=qp[2].x,q5=qp[2].y,q6=qp[3].x,q7=qp[3].y;

      // reduce-scatter butterfly: lane ends with full logit for k = lane&7
      float r0 = c0 ? q0 : q1, r1 = c0 ? q2 : q3, r2 = c0 ? q4 : q5, r3 = c0 ? q6 : q7;
      r0 = __shfl_xor(r0, 1, 64); r1 = __shfl_xor(r1, 1, 64);
      r2 = __shfl_xor(r2, 1, 64); r3 = __shfl_xor(r3, 1, 64);
      float a0 = (c0 ? q1 : q0) + r0, a1 = (c0 ? q3 : q2) + r1;
      float a2 = (c0 ? q5 : q4) + r2, a3 = (c0 ? q7 : q6) + r3;
      float s0g = c1 ? a0 : a1, s1g = c1 ? a2 : a3;
      s0g = __shfl_xor(s0g, 2, 64); s1g = __shfl_xor(s1g, 2, 64);
      float b0 = (c1 ? a1 : a0) + s0g, b1 = (c1 ? a3 : a2) + s1g;
      float g0 = c2 ? b0 : b1;
      g0 = __shfl_xor(g0, 4, 64);
      float t = (c2 ? b1 : b0) + g0;
      t += __shfl_xor(t, 8, 64);
      t += __shfl_xor(t, 16, 64);
      t += __shfl_xor(t, 32, 64);
      t += biasv;

      // softmax in transposed (one-k-per-lane) form
      float mx = fmaxf(t, __shfl_xor(t, 1, 64));
      mx = fmaxf(mx, __shfl_xor(mx, 2, 64));
      mx = fmaxf(mx, __shfl_xor(mx, 4, 64));
      float e = __expf(t - mx);
      float se = e + __shfl_xor(e, 1, 64);
      se += __shfl_xor(se, 2, 64);
      se += __shfl_xor(se, 4, 64);
      float pm = e * __builtin_amdgcn_rcpf(se);

      s0acc += pm;
      psel = (grp == j) ? pm : psel;   // lane (grp,j) keeps row j's p[lane&7]
    }
    // coalesced store: rows batch*8..batch*8+7, P[row][k] at lane = j*8+k
    Pb[batch * 64 + lane] = psel;
  }

  // S0 per chunk: s0acc (replicated per k-lane) -> LDS -> per-block sum
  __shared__ float s0sh[WAVES][K_];
  if (lane < K_) s0sh[wave][lane] = s0acc;
  __syncthreads();
  if (threadIdx.x < K_) {
    float s = 0.f;
#pragma unroll
    for (int w = 0; w < WAVES; ++w) s += s0sh[w][threadIdx.x];
    const int cslot = atomic_mode ? 0 : chunk;
    float* dst = s0p + (size_t)(b * cstride + cslot) * K_ + threadIdx.x;
    if (atomic_mode) atomicAdd(dst, s); else *dst = s;
  }
}

__global__ __launch_bounds__(512, 2)
void kB_moments(const float* __restrict__ x, const float* __restrict__ P,
                float* __restrict__ partial, int cstride, int atomic_mode) {
#pragma clang fp contract(fast)
  const int lane = threadIdx.x & 63;
  const int wave = threadIdx.x >> 6;
  const int b    = blockIdx.x >> 5;
  const int chunk= blockIdx.x & 31;

  v2f acc[8][8];
#pragma unroll
  for (int dj = 0; dj < 8; ++dj)
#pragma unroll
    for (int k = 0; k < 8; ++k) acc[dj][k] = (v2f){0.f, 0.f};

  const int row_base = chunk * (WAVES * ROWS_PER_WAVE) + wave * ROWS_PER_WAVE;
  const float* xb = x + (size_t)b * N_ * D_;
  const float* Prow = P + ((size_t)b * N_ + row_base) * K_;

  // software-pipelined row loop (x + p prefetch)
  const float4* xr = reinterpret_cast<const float4*>(&xb[(size_t)row_base * D_]);
  float4 xa = xr[lane];
  float4 xc = xr[64 + lane];
  const float4* pr = reinterpret_cast<const float4*>(Prow);
  float4 pA = pr[0], pB = pr[1];

  for (int i = 0; i < ROWS_PER_WAVE; ++i) {
    const int ni = (i + 1 < ROWS_PER_WAVE) ? i + 1 : i;
    const float4* xrn = reinterpret_cast<const float4*>(&xb[(size_t)(row_base + ni) * D_]);
    float4 na = xrn[lane];
    float4 nc = xrn[64 + lane];
    const float4* prn = reinterpret_cast<const float4*>(Prow + (size_t)ni * K_);
    float4 npA = prn[0], npB = prn[1];

    float xv[8] = {xa.x, xa.y, xa.z, xa.w, xc.x, xc.y, xc.z, xc.w};
    float pk[8] = {pA.x, pA.y, pA.z, pA.w, pB.x, pB.y, pB.z, pB.w};

#pragma unroll
    for (int dj = 0; dj < 8; ++dj) {
      v2f m2 = (v2f){xv[dj], xv[dj] * xv[dj]};
#pragma unroll
      for (int k = 0; k < 8; ++k) {
        v2f pp = (v2f){pk[k], pk[k]};
        acc[dj][k] += m2 * pp;
      }
    }

    xa = na; xc = nc; pA = npA; pB = npB;
  }

  // ---- block-level LDS tree reduction & non-atomic flush ----
  const int cslot = atomic_mode ? 0 : chunk;
  __shared__ v2f sh[WAVES][2][K_][64];   // 64 KB

#pragma unroll
  for (int r = 0; r < 4; ++r) {
#pragma unroll
    for (int k = 0; k < 8; ++k) {
      sh[wave][0][k][lane] = acc[2*r][k];
      sh[wave][1][k][lane] = acc[2*r + 1][k];
    }
    __syncthreads();
    // wave w reduces k=w across waves; lanes cover the 64 d-slots
    v2f sA = sh[0][0][wave][lane];
    v2f sB = sh[0][1][wave][lane];
#pragma unroll
    for (int w = 1; w < WAVES; ++w) {
      sA += sh[w][0][wave][lane];
      sB += sh[w][1][wave][lane];
    }
    const int d = (r < 2) ? (lane * 4 + 2 * r) : (256 + lane * 4 + (2 * r - 4));
    float* dst = partial + (((size_t)(b * cstride + cslot) * K_ + wave) * D_ + d) * 2;
    if (atomic_mode) {
      atomicAdd(dst + 0, sA.x); atomicAdd(dst + 1, sA.y);
      atomicAdd(dst + 2, sB.x); atomicAdd(dst + 3, sB.y);
    } else {
      float4 v; v.x = sA.x; v.y = sA.y; v.z = sB.x; v.w = sB.y;
      *reinterpret_cast<float4*>(dst) = v;   // d even -> 16B aligned
    }
    __syncthreads();
  }
}

// Fused finalizer: grid = B*32 blocks, 128 threads (8 k x 16 d).
__global__ __launch_bounds__(128)
void k2_final(const float* __restrict__ partial, const float* __restrict__ s0p,
              const float* __restrict__ eps, float* __restrict__ out,
              int cstride, int nchunks) {
  const int b = blockIdx.x >> 5;
  const int slice = blockIdx.x & 31;
  const int tid = threadIdx.x;
  const int k = tid >> 4;
  const int dl = tid & 15;
  const int d = slice * 16 + dl;

  __shared__ float s0sh[K_];
  __shared__ float zsh[K_][16];
  __shared__ float klsh[2];

  if (tid < K_) {
    float s = 0.f;
    for (int c = 0; c < nchunks; ++c) s += s0p[(size_t)(b * cstride + c) * K_ + tid];
    s0sh[tid] = s;
  }
  __syncthreads();

  float S1 = 0.f, S2 = 0.f;
  for (int c = 0; c < nchunks; ++c) {
    const v2f v = *reinterpret_cast<const v2f*>(
        partial + (((size_t)(b * cstride + c) * K_ + k) * D_ + d) * 2);
    S1 += v.x; S2 += v.y;
  }
  const float S0 = s0sh[k];
  float sigraw = S2 + (S0 - 2.f) * S1 * S1;
  float sig = fmaxf(sigraw, 0.f) + EPS_;
  float z = S1 + eps[((size_t)(b * K_ + k)) * D_ + d] * sqrtf(sig);
  zsh[k][dl] = z;
  float klp = 1.f + logf(sig) - S1 * S1 - sigraw;

  klp += __shfl_xor(klp, 1, 64);
  klp += __shfl_xor(klp, 2, 64);
  klp += __shfl_xor(klp, 4, 64);
  klp += __shfl_xor(klp, 8, 64);
  klp += __shfl_xor(klp, 16, 64);
  klp += __shfl_xor(klp, 32, 64);
  const int lane = tid & 63, wv = tid >> 6;
  if (lane == 0) klsh[wv] = klp;
  __syncthreads();

  if (tid < 16) {
    float pooled = 0.f;
#pragma unroll
    for (int kk = 0; kk < K_; ++kk) pooled += zsh[kk][tid];
    out[b * D_ + slice * 16 + tid] = pooled * 0.125f;
  }
  if (tid == 0) {
    atomicAdd(out + B_ * D_, (klsh[0] + klsh[1]) * (-0.5f / (B_ * K_)));
  }
}

extern "C" void kernel_launch(void* const* d_in, const int* in_sizes, int n_in,
                              void* d_out, int out_size, void* d_ws, size_t ws_size,
                              hipStream_t stream) {
  const float* x    = (const float*)d_in[0];
  const float* W    = (const float*)d_in[1];
  const float* bias = (const float*)d_in[2];
  const float* eps  = (const float*)d_in[3];
  float* out = (float*)d_out;
  float* ws  = (float*)d_ws;

  const size_t full_floats =
      P_FLOATS + (size_t)B_ * CHUNKS * K_ * D_ * 2 + (size_t)B_ * CHUNKS * K_;
  const int atomic_mode = (ws_size < full_floats * sizeof(float)) ? 1 : 0;
  const int cstride = atomic_mode ? 1 : CHUNKS;
  const int nchunks = atomic_mode ? 1 : CHUNKS;

  float* P       = ws;
  float* partial = ws + P_FLOATS;
  float* s0p     = partial + (size_t)B_ * cstride * K_ * D_ * 2;

  if (atomic_mode) {
    const size_t zbytes =
        ((size_t)B_ * K_ * D_ * 2 + (size_t)B_ * K_) * sizeof(float);
    hipMemsetAsync(partial, 0, zbytes, stream);
  }
  hipMemsetAsync(out + B_ * D_, 0, sizeof(float), stream);

  kA_probs  <<<B_ * CHUNKS, 64 * WAVES, 0, stream>>>(x, W, bias, P, s0p, cstride, atomic_mode);
  kB_moments<<<B_ * CHUNKS, 64 * WAVES, 0, stream>>>(x, P, partial, cstride, atomic_mode);
  k2_final  <<<B_ * 32, 128, 0, stream>>>(partial, s0p, eps, out, cstride, nchunks);
}